// Round 2
// baseline (214.574 us; speedup 1.0000x reference)
//
#include <hip/hip_runtime.h>

typedef unsigned short u16;
typedef unsigned int u32;
typedef __attribute__((ext_vector_type(8))) short bf16x8;
typedef __attribute__((ext_vector_type(8))) unsigned short u16x8;
typedef __attribute__((ext_vector_type(4))) float f32x4;

#define GLOBAL_AS __attribute__((address_space(1)))
#define LDS_AS __attribute__((address_space(3)))

#define BIGV 1.0e12f
#define M0PIV 1.25e11f

__device__ __forceinline__ u16 f2bf(float f) {
  u32 u = __float_as_uint(f);
  u32 r = (u + 0x7fffu + ((u >> 16) & 1u)) >> 16;
  return (u16)r;
}
__device__ __forceinline__ float bf2f(u16 h) {
  return __uint_as_float(((u32)h) << 16);
}

// ---------------- prep kernels ----------------

__global__ __launch_bounds__(256) void k_cvt_lhs(const float4* __restrict__ in,
                                                 ushort4* __restrict__ out) {
  int t = blockIdx.x * 256 + threadIdx.x;  // 1572864 total
  float4 v = in[t];
  ushort4 o;
  o.x = f2bf(v.x); o.y = f2bf(v.y); o.z = f2bf(v.z); o.w = f2bf(v.w);
  out[t] = o;
}

__global__ __launch_bounds__(256) void k_transpose_w(const float* __restrict__ W,
                                                     u16* __restrict__ WT) {
  __shared__ float tile[32][33];
  int tx = threadIdx.x, ty = threadIdx.y;             // (32,8)
  int gx = blockIdx.x * 32, gy = blockIdx.y * 32;     // gx: cols of W(1024), gy: rows (768)
  #pragma unroll
  for (int i = 0; i < 4; ++i)
    tile[ty + 8 * i][tx] = W[(size_t)(gy + ty + 8 * i) * 1024 + gx + tx];
  __syncthreads();
  #pragma unroll
  for (int i = 0; i < 4; ++i)
    WT[(size_t)(gx + ty + 8 * i) * 768 + gy + tx] = f2bf(tile[tx][ty + 8 * i]);
}

__global__ __launch_bounds__(256) void k_table(float2* __restrict__ tab) {
  int t = blockIdx.x * 256 + threadIdx.x;  // 16384 = 1024 pos * 16 freq
  int p = t >> 4, i = t & 15;
  float freq = __expf(-0.57564627324851148f * (float)i);  // ln(10000)/16
  float ang = (float)p * freq;
  float s, c;
  sincosf(ang, &s, &c);
  tab[t] = make_float2(s, c);
}

// ---------------- stage 1: proj = lhs @ W + b (bf16 MFMA, 128x128 tile, BK=64) ----------------

__global__ __launch_bounds__(256) void k_gemm1(const u16* __restrict__ A,   // [8192][768] bf16
                                               const u16* __restrict__ WT,  // [1024][768] bf16
                                               const float* __restrict__ bias,
                                               u16* __restrict__ qws,       // [128][512][64] bf16
                                               u16* __restrict__ kws) {
  __shared__ __align__(16) u16 As[128 * 64];
  __shared__ __align__(16) u16 Bs[128 * 64];
  const int tid = threadIdx.x;
  const int wave = tid >> 6, lane = tid & 63;
  const int lg = lane >> 4, lr = lane & 15;
  const int m0 = blockIdx.x * 128;
  const int e = blockIdx.y;
  const int n0 = e * 128;
  const int wr = wave >> 1, wc = wave & 1;

  f32x4 acc[4][4];
  #pragma unroll
  for (int i = 0; i < 4; ++i)
    #pragma unroll
    for (int j = 0; j < 4; ++j)
      acc[i][j] = (f32x4){0.f, 0.f, 0.f, 0.f};

  for (int k0 = 0; k0 < 768; k0 += 64) {
    #pragma unroll
    for (int i = 0; i < 4; ++i) {
      int u = (i * 4 + wave) * 64 + lane;
      int r = u >> 3, sl = u & 7;
      const u16* srcA = A + (size_t)(m0 + r) * 768 + k0 + ((sl ^ (r & 7)) * 8);
      __builtin_amdgcn_global_load_lds((const GLOBAL_AS void*)srcA,
                                       (LDS_AS void*)(As + (i * 4 + wave) * 512), 16, 0, 0);
      const u16* srcB = WT + (size_t)(n0 + r) * 768 + k0 + ((sl ^ (r & 7)) * 8);
      __builtin_amdgcn_global_load_lds((const GLOBAL_AS void*)srcB,
                                       (LDS_AS void*)(Bs + (i * 4 + wave) * 512), 16, 0, 0);
    }
    __syncthreads();
    #pragma unroll
    for (int ks = 0; ks < 2; ++ks) {
      bf16x8 af[4], bfr[4];
      #pragma unroll
      for (int mi = 0; mi < 4; ++mi) {
        int r = wr * 64 + mi * 16 + lr;
        int slot = (ks * 4 + lg) ^ (r & 7);
        af[mi] = *reinterpret_cast<const bf16x8*>(As + r * 64 + slot * 8);
      }
      #pragma unroll
      for (int ni = 0; ni < 4; ++ni) {
        int r = wc * 64 + ni * 16 + lr;
        int slot = (ks * 4 + lg) ^ (r & 7);
        bfr[ni] = *reinterpret_cast<const bf16x8*>(Bs + r * 64 + slot * 8);
      }
      #pragma unroll
      for (int mi = 0; mi < 4; ++mi)
        #pragma unroll
        for (int ni = 0; ni < 4; ++ni)
          acc[mi][ni] = __builtin_amdgcn_mfma_f32_16x16x32_bf16(af[mi], bfr[ni], acc[mi][ni], 0, 0, 0);
    }
    __syncthreads();
  }

  #pragma unroll
  for (int mi = 0; mi < 4; ++mi) {
    #pragma unroll
    for (int ni = 0; ni < 4; ++ni) {
      int nloc = wc * 64 + ni * 16 + lr;   // 0..127 within entity
      float bv = bias[n0 + nloc];
      int d = nloc & 63;
      u16* dst = (nloc < 64) ? qws : kws;
      #pragma unroll
      for (int q = 0; q < 4; ++q) {
        int m = m0 + wr * 64 + mi * 16 + lg * 4 + q;   // global row = b*512+s
        int bi = m >> 9, sdx = m & 511;
        float v = acc[mi][ni][q] + bv;
        dst[(((size_t)(bi * 8 + e) * 512 + sdx) << 6) + d] = f2bf(v);
      }
    }
  }
}

// ---------------- RoPE (in place on qws/kws) ----------------

__global__ __launch_bounds__(256) void k_rope(u16* __restrict__ qws, u16* __restrict__ kws,
                                              const int* __restrict__ bbox,
                                              const float2* __restrict__ tab) {
  int t = blockIdx.x * 256 + threadIdx.x;  // 1048576 = 2 * 65536 rows * 8 units
  int arr = t >> 19;
  int u = t & 524287;
  int rid = u >> 3;        // be*512 + s
  int d0 = (u & 7) * 8;
  int be = rid >> 9, s = rid & 511;
  int b = be >> 3;
  int x = bbox[((b << 9) + s) * 4 + 0];
  int y = bbox[((b << 9) + s) * 4 + 1];
  u16* base = (arr ? kws : qws) + ((size_t)rid << 6) + d0;
  u16x8 v = *reinterpret_cast<const u16x8*>(base);
  u16x8 o;
  #pragma unroll
  for (int j = 0; j < 8; j += 2) {
    int d = d0 + j;
    int pos = (d < 32) ? x : y;
    int fi = (d & 31) >> 1;
    float2 sc = tab[pos * 16 + fi];   // (sin, cos)
    float v0 = bf2f(v[j]), v1 = bf2f(v[j + 1]);
    o[j] = f2bf(v0 * sc.y - v1 * sc.x);
    o[j + 1] = f2bf(v1 * sc.y + v0 * sc.x);
  }
  *reinterpret_cast<u16x8*>(base) = o;
}

// ---------------- stage 2: logits + masked scaling + fixed-pivot LSE partial sums ----------------
// neg side: pivot 0   -> sum_n = sum exp(an); masked entries underflow to exactly 0
// pos side: pivot M0PIV=BIG/8 -> sum_p = sum exp(ap - M0PIV); small entries underflow (match ref LSE)

__global__ __launch_bounds__(256) void k_logits_loss(const u16* __restrict__ qws,
                                                     const u16* __restrict__ kws,
                                                     const int* __restrict__ mask,
                                                     const int* __restrict__ labels,
                                                     float* __restrict__ out,
                                                     float2* __restrict__ partials) {
  __shared__ __align__(16) u16 Qs[64 * 64];
  __shared__ __align__(16) u16 Ks[128 * 64];
  __shared__ float2 wred[4];
  const int tid = threadIdx.x;
  const int wave = tid >> 6, lane = tid & 63;
  const int lg = lane >> 4, lr = lane & 15;
  const int be = blockIdx.x, mb = blockIdx.y;   // mb 0..7 (64 q-rows each)
  const int b = be >> 3;
  const int m0 = mb * 64;

  const u16* qbase = qws + ((size_t)be * 512 + m0) * 64;
  const u16* kbase = kws + (size_t)be * 512 * 64;

  // stage Q block (64x64 bf16 = 512 x 16B units), XOR-swizzled source
  #pragma unroll
  for (int i = 0; i < 2; ++i) {
    int u = (i * 4 + wave) * 64 + lane;
    int r = u >> 3, sl = u & 7;
    const u16* src = qbase + r * 64 + ((sl ^ (r & 7)) * 8);
    __builtin_amdgcn_global_load_lds((const GLOBAL_AS void*)src,
                                     (LDS_AS void*)(Qs + (i * 4 + wave) * 512), 16, 0, 0);
  }

  float sum_n = 0.f, sum_p = 0.f;

  for (int cc = 0; cc < 4; ++cc) {
    #pragma unroll
    for (int i = 0; i < 4; ++i) {
      int u = (i * 4 + wave) * 64 + lane;
      int r = u >> 3, sl = u & 7;
      const u16* src = kbase + (size_t)(cc * 128 + r) * 64 + ((sl ^ (r & 7)) * 8);
      __builtin_amdgcn_global_load_lds((const GLOBAL_AS void*)src,
                                       (LDS_AS void*)(Ks + (i * 4 + wave) * 512), 16, 0, 0);
    }
    __syncthreads();

    f32x4 acc[8];
    #pragma unroll
    for (int ni = 0; ni < 8; ++ni) acc[ni] = (f32x4){0.f, 0.f, 0.f, 0.f};

    #pragma unroll
    for (int ks = 0; ks < 2; ++ks) {
      bf16x8 a0;
      {
        int r = wave * 16 + lr;
        int slot = (ks * 4 + lg) ^ (r & 7);
        a0 = *reinterpret_cast<const bf16x8*>(Qs + r * 64 + slot * 8);
      }
      #pragma unroll
      for (int ni = 0; ni < 8; ++ni) {
        int r = ni * 16 + lr;
        int slot = (ks * 4 + lg) ^ (r & 7);
        bf16x8 bv = *reinterpret_cast<const bf16x8*>(Ks + r * 64 + slot * 8);
        acc[ni] = __builtin_amdgcn_mfma_f32_16x16x32_bf16(a0, bv, acc[ni], 0, 0, 0);
      }
    }

    #pragma unroll
    for (int ni = 0; ni < 8; ++ni) {
      int n = cc * 128 + ni * 16 + lr;
      float pad = (float)mask[(b << 9) + n];
      float mterm = (1.f - pad) * BIGV;
      #pragma unroll
      for (int q = 0; q < 4; ++q) {
        int m = m0 + wave * 16 + lg * 4 + q;
        float L = acc[ni][q] * pad - mterm;
        if (m > n) L -= BIGV;
        L *= 0.125f;
        size_t idx = (((size_t)be * 512) + m) * 512 + n;
        __builtin_nontemporal_store(L, &out[1 + idx]);
        float fy = (float)__builtin_nontemporal_load(&labels[idx]);
        float t1 = (1.f - 2.f * fy) * L;
        float an = t1 - fy * BIGV;
        float ap = t1 - (1.f - fy) * BIGV - M0PIV;
        sum_n += __expf(fminf(an, 80.f));
        sum_p += __expf(fminf(ap, 80.f));
      }
    }
    __syncthreads();
  }

  // reduce plain sums across the wave, then block
  #pragma unroll
  for (int off = 32; off > 0; off >>= 1) {
    sum_n += __shfl_xor(sum_n, off);
    sum_p += __shfl_xor(sum_p, off);
  }
  if (lane == 0) wred[wave] = make_float2(sum_n, sum_p);
  __syncthreads();
  if (tid == 0) {
    float2 r0 = wred[0];
    for (int w = 1; w < 4; ++w) {
      float2 rw = wred[w];
      r0.x += rw.x;
      r0.y += rw.y;
    }
    partials[be * 8 + mb] = r0;
  }
}

// ---------------- final: combine partials, mean, write loss ----------------

__global__ __launch_bounds__(128) void k_final(const float2* __restrict__ partials,
                                               float* __restrict__ out) {
  __shared__ float red[128];
  int t = threadIdx.x;  // = be
  float Sn = 0.f, Sp = 0.f;
  for (int mb = 0; mb < 8; ++mb) {
    float2 p = partials[t * 8 + mb];
    Sn += p.x;
    Sp += p.y;
  }
  float neg = logf(1.f + Sn);                        // appended-zero entry = +1 at pivot 0
  float pos = (Sp > 0.f) ? (M0PIV + logf(Sp)) : 0.f; // zero entry underflows at pivot M0
  red[t] = neg + pos;
  __syncthreads();
  if (t == 0) {
    float s = 0.f;
    for (int i = 0; i < 128; ++i) s += red[i];
    out[0] = s * (1.f / 128.f);
  }
}

// ---------------- launch ----------------

extern "C" void kernel_launch(void* const* d_in, const int* in_sizes, int n_in,
                              void* d_out, int out_size, void* d_ws, size_t ws_size,
                              hipStream_t stream) {
  const float* lhs = (const float*)d_in[0];     // (16,512,768) f32
  const float* W = (const float*)d_in[1];       // (768,1024) f32
  const float* bias = (const float*)d_in[2];    // (1024,) f32
  const int* mask = (const int*)d_in[3];        // (16,512) i32
  const int* bbox = (const int*)d_in[4];        // (16,512,4) i32
  const int* labels = (const int*)d_in[5];      // (16,8,512,512) i32
  float* out = (float*)d_out;                   // [loss(1)] + logits (16,8,512,512) f32

  char* ws = (char*)d_ws;
  u16* lhsb = (u16*)(ws);                       // 12582912 B
  u16* wt = (u16*)(ws + 12582912);              // 1572864 B
  u16* qws = (u16*)(ws + 14155776);             // 8388608 B
  u16* kws = (u16*)(ws + 22544384);             // 8388608 B
  float2* tab = (float2*)(ws + 30932992);       // 131072 B
  float2* partials = (float2*)(ws + 31064064);  // 8192 B

  k_cvt_lhs<<<6144, 256, 0, stream>>>((const float4*)lhs, (ushort4*)lhsb);
  k_transpose_w<<<dim3(32, 24), dim3(32, 8), 0, stream>>>(W, wt);
  k_table<<<64, 256, 0, stream>>>(tab);
  k_gemm1<<<dim3(64, 8), 256, 0, stream>>>(lhsb, wt, bias, qws, kws);
  k_rope<<<4096, 256, 0, stream>>>(qws, kws, bbox, tab);
  k_logits_loss<<<dim3(128, 8), 256, 0, stream>>>(qws, kws, mask, labels, out, partials);
  k_final<<<1, 128, 0, stream>>>(partials, out);
}

// Round 3
// 117.308 us; speedup vs baseline: 1.8292x; 1.8292x over previous
//
#include <hip/hip_runtime.h>

typedef unsigned short u16;
typedef unsigned int u32;
typedef __attribute__((ext_vector_type(8))) short bf16x8;
typedef __attribute__((ext_vector_type(8))) unsigned short u16x8;
typedef __attribute__((ext_vector_type(4))) float f32x4;

#define GLOBAL_AS __attribute__((address_space(1)))
#define LDS_AS __attribute__((address_space(3)))

#define BIGV 1.0e12f
#define M0PIV 1.25e11f

__device__ __forceinline__ u16 f2bf(float f) {
  u32 u = __float_as_uint(f);
  u32 r = (u + 0x7fffu + ((u >> 16) & 1u)) >> 16;
  return (u16)r;
}
__device__ __forceinline__ float bf2f(u16 h) {
  return __uint_as_float(((u32)h) << 16);
}

// ---------------- prep kernels ----------------

__global__ __launch_bounds__(256) void k_cvt_lhs(const float4* __restrict__ in,
                                                 ushort4* __restrict__ out) {
  int t = blockIdx.x * 256 + threadIdx.x;  // 1572864 total
  float4 v = in[t];
  ushort4 o;
  o.x = f2bf(v.x); o.y = f2bf(v.y); o.z = f2bf(v.z); o.w = f2bf(v.w);
  out[t] = o;
}

__global__ __launch_bounds__(256) void k_transpose_w(const float* __restrict__ W,
                                                     u16* __restrict__ WT) {
  __shared__ float tile[32][33];
  int tx = threadIdx.x, ty = threadIdx.y;             // (32,8)
  int gx = blockIdx.x * 32, gy = blockIdx.y * 32;     // gx: cols of W(1024), gy: rows (768)
  #pragma unroll
  for (int i = 0; i < 4; ++i)
    tile[ty + 8 * i][tx] = W[(size_t)(gy + ty + 8 * i) * 1024 + gx + tx];
  __syncthreads();
  #pragma unroll
  for (int i = 0; i < 4; ++i)
    WT[(size_t)(gx + ty + 8 * i) * 768 + gy + tx] = f2bf(tile[tx][ty + 8 * i]);
}

__global__ __launch_bounds__(256) void k_table(float2* __restrict__ tab) {
  int t = blockIdx.x * 256 + threadIdx.x;  // 16384 = 1024 pos * 16 freq
  int p = t >> 4, i = t & 15;
  float freq = __expf(-0.57564627324851148f * (float)i);  // ln(10000)/16
  float ang = (float)p * freq;
  float s, c;
  sincosf(ang, &s, &c);
  tab[t] = make_float2(s, c);
}

// ------- stage 1: proj = lhs @ W + b, fused RoPE epilogue (bf16 MFMA, 128x128 tile, BK=64) -------

__global__ __launch_bounds__(256) void k_gemm1(const u16* __restrict__ A,   // [8192][768] bf16
                                               const u16* __restrict__ WT,  // [1024][768] bf16
                                               const float* __restrict__ bias,
                                               const int2* __restrict__ bbox2,  // (x,y) pairs stride 2
                                               const float2* __restrict__ tab,
                                               u16* __restrict__ qws,       // [128][512][64] bf16
                                               u16* __restrict__ kws) {
  __shared__ __align__(16) u16 As[128 * 64];
  __shared__ __align__(16) u16 Bs[128 * 64];
  const int tid = threadIdx.x;
  const int wave = tid >> 6, lane = tid & 63;
  const int lg = lane >> 4, lr = lane & 15;
  const int m0 = blockIdx.x * 128;
  const int e = blockIdx.y;
  const int n0 = e * 128;
  const int wr = wave >> 1, wc = wave & 1;

  f32x4 acc[4][4];
  #pragma unroll
  for (int i = 0; i < 4; ++i)
    #pragma unroll
    for (int j = 0; j < 4; ++j)
      acc[i][j] = (f32x4){0.f, 0.f, 0.f, 0.f};

  for (int k0 = 0; k0 < 768; k0 += 64) {
    #pragma unroll
    for (int i = 0; i < 4; ++i) {
      int u = (i * 4 + wave) * 64 + lane;
      int r = u >> 3, sl = u & 7;
      const u16* srcA = A + (size_t)(m0 + r) * 768 + k0 + ((sl ^ (r & 7)) * 8);
      __builtin_amdgcn_global_load_lds((const GLOBAL_AS void*)srcA,
                                       (LDS_AS void*)(As + (i * 4 + wave) * 512), 16, 0, 0);
      const u16* srcB = WT + (size_t)(n0 + r) * 768 + k0 + ((sl ^ (r & 7)) * 8);
      __builtin_amdgcn_global_load_lds((const GLOBAL_AS void*)srcB,
                                       (LDS_AS void*)(Bs + (i * 4 + wave) * 512), 16, 0, 0);
    }
    __syncthreads();
    #pragma unroll
    for (int ks = 0; ks < 2; ++ks) {
      bf16x8 af[4], bfr[4];
      #pragma unroll
      for (int mi = 0; mi < 4; ++mi) {
        int r = wr * 64 + mi * 16 + lr;
        int slot = (ks * 4 + lg) ^ (r & 7);
        af[mi] = *reinterpret_cast<const bf16x8*>(As + r * 64 + slot * 8);
      }
      #pragma unroll
      for (int ni = 0; ni < 4; ++ni) {
        int r = wc * 64 + ni * 16 + lr;
        int slot = (ks * 4 + lg) ^ (r & 7);
        bfr[ni] = *reinterpret_cast<const bf16x8*>(Bs + r * 64 + slot * 8);
      }
      #pragma unroll
      for (int mi = 0; mi < 4; ++mi)
        #pragma unroll
        for (int ni = 0; ni < 4; ++ni)
          acc[mi][ni] = __builtin_amdgcn_mfma_f32_16x16x32_bf16(af[mi], bfr[ni], acc[mi][ni], 0, 0, 0);
    }
    __syncthreads();
  }

  // epilogue: bias + RoPE (partner via shfl_xor(1)) + bf16 scatter
  float bv[4];
  #pragma unroll
  for (int ni = 0; ni < 4; ++ni) bv[ni] = bias[n0 + wc * 64 + ni * 16 + lr];

  #pragma unroll
  for (int mi = 0; mi < 4; ++mi) {
    #pragma unroll
    for (int q = 0; q < 4; ++q) {
      int m = m0 + wr * 64 + mi * 16 + lg * 4 + q;   // global row = b*512+s
      int bi = m >> 9, sdx = m & 511;
      int2 xy = bbox2[(bi << 9) + sdx];
      size_t rowbase = ((size_t)(bi * 8 + e) * 512 + sdx) << 6;
      #pragma unroll
      for (int ni = 0; ni < 4; ++ni) {
        int nloc = wc * 64 + ni * 16 + lr;   // 0..127 within entity
        int d = nloc & 63;
        float v = acc[mi][ni][q] + bv[ni];
        float p = __shfl_xor(v, 1);
        int pos = (d < 32) ? xy.x : xy.y;
        float2 sc = tab[pos * 16 + ((d & 31) >> 1)];  // (sin, cos)
        float res = (d & 1) ? (v * sc.y + p * sc.x) : (v * sc.y - p * sc.x);
        u16* dst = (nloc < 64) ? qws : kws;
        dst[rowbase + d] = f2bf(res);
      }
    }
  }
}

// ---------------- stage 2: logits + masked scaling + fixed-pivot LSE partial sums ----------------
// neg side: pivot 0          -> sum_n = sum exp(an); masked entries underflow to exactly 0
// pos side: pivot M0PIV=BIG/8 -> sum_p = sum exp(ap - M0PIV); small entries underflow (match ref)

__global__ __launch_bounds__(256) void k_logits_loss(const u16* __restrict__ qws,
                                                     const u16* __restrict__ kws,
                                                     const int* __restrict__ mask,
                                                     const int* __restrict__ labels,
                                                     float* __restrict__ out,
                                                     float2* __restrict__ partials) {
  __shared__ __align__(16) u16 Qs[64 * 64];
  __shared__ __align__(16) u16 Ks[128 * 64];
  __shared__ float2 wred[4];
  const int tid = threadIdx.x;
  const int wave = tid >> 6, lane = tid & 63;
  const int lg = lane >> 4, lr = lane & 15;
  const int mb = blockIdx.x, be = blockIdx.y;   // mb fastest: blocks sharing K are adjacent
  const int b = be >> 3;
  const int m0 = mb * 64;

  const u16* qbase = qws + ((size_t)be * 512 + m0) * 64;
  const u16* kbase = kws + (size_t)be * 512 * 64;

  // stage Q block (64x64 bf16 = 512 x 16B units), XOR-swizzled source
  #pragma unroll
  for (int i = 0; i < 2; ++i) {
    int u = (i * 4 + wave) * 64 + lane;
    int r = u >> 3, sl = u & 7;
    const u16* src = qbase + r * 64 + ((sl ^ (r & 7)) * 8);
    __builtin_amdgcn_global_load_lds((const GLOBAL_AS void*)src,
                                     (LDS_AS void*)(Qs + (i * 4 + wave) * 512), 16, 0, 0);
  }

  float sum_n = 0.f, sum_p = 0.f;

  for (int cc = 0; cc < 4; ++cc) {
    #pragma unroll
    for (int i = 0; i < 4; ++i) {
      int u = (i * 4 + wave) * 64 + lane;
      int r = u >> 3, sl = u & 7;
      const u16* src = kbase + (size_t)(cc * 128 + r) * 64 + ((sl ^ (r & 7)) * 8);
      __builtin_amdgcn_global_load_lds((const GLOBAL_AS void*)src,
                                       (LDS_AS void*)(Ks + (i * 4 + wave) * 512), 16, 0, 0);
    }
    __syncthreads();

    f32x4 acc[8];
    #pragma unroll
    for (int ni = 0; ni < 8; ++ni) acc[ni] = (f32x4){0.f, 0.f, 0.f, 0.f};

    #pragma unroll
    for (int ks = 0; ks < 2; ++ks) {
      bf16x8 a0;
      {
        int r = wave * 16 + lr;
        int slot = (ks * 4 + lg) ^ (r & 7);
        a0 = *reinterpret_cast<const bf16x8*>(Qs + r * 64 + slot * 8);
      }
      #pragma unroll
      for (int ni = 0; ni < 8; ++ni) {
        int r = ni * 16 + lr;
        int slot = (ks * 4 + lg) ^ (r & 7);
        bf16x8 bv = *reinterpret_cast<const bf16x8*>(Ks + r * 64 + slot * 8);
        acc[ni] = __builtin_amdgcn_mfma_f32_16x16x32_bf16(a0, bv, acc[ni], 0, 0, 0);
      }
    }

    #pragma unroll
    for (int ni = 0; ni < 8; ++ni) {
      int n = cc * 128 + ni * 16 + lr;
      float pad = (float)mask[(b << 9) + n];
      float mterm = (1.f - pad) * BIGV;
      #pragma unroll
      for (int q = 0; q < 4; ++q) {
        int m = m0 + wave * 16 + lg * 4 + q;
        float L = acc[ni][q] * pad - mterm;
        if (m > n) L -= BIGV;
        L *= 0.125f;
        size_t idx = (((size_t)be * 512) + m) * 512 + n;
        out[1 + idx] = L;
        float fy = (float)labels[idx];
        float t1 = (1.f - 2.f * fy) * L;
        float an = t1 - fy * BIGV;
        float ap = t1 - (1.f - fy) * BIGV - M0PIV;
        sum_n += __expf(fminf(an, 80.f));
        sum_p += __expf(fminf(ap, 80.f));
      }
    }
    __syncthreads();
  }

  // reduce plain sums across the wave, then block
  #pragma unroll
  for (int off = 32; off > 0; off >>= 1) {
    sum_n += __shfl_xor(sum_n, off);
    sum_p += __shfl_xor(sum_p, off);
  }
  if (lane == 0) wred[wave] = make_float2(sum_n, sum_p);
  __syncthreads();
  if (tid == 0) {
    float2 r0 = wred[0];
    for (int w = 1; w < 4; ++w) {
      float2 rw = wred[w];
      r0.x += rw.x;
      r0.y += rw.y;
    }
    partials[be * 8 + mb] = r0;
  }
}

// ---------------- final: combine partials, mean, write loss ----------------

__global__ __launch_bounds__(128) void k_final(const float2* __restrict__ partials,
                                               float* __restrict__ out) {
  __shared__ float red[128];
  int t = threadIdx.x;  // = be
  float Sn = 0.f, Sp = 0.f;
  for (int mb = 0; mb < 8; ++mb) {
    float2 p = partials[t * 8 + mb];
    Sn += p.x;
    Sp += p.y;
  }
  float neg = logf(1.f + Sn);                        // appended-zero entry = +1 at pivot 0
  float pos = (Sp > 0.f) ? (M0PIV + logf(Sp)) : 0.f; // zero entry underflows at pivot M0
  red[t] = neg + pos;
  __syncthreads();
  if (t == 0) {
    float s = 0.f;
    for (int i = 0; i < 128; ++i) s += red[i];
    out[0] = s * (1.f / 128.f);
  }
}

// ---------------- launch ----------------

extern "C" void kernel_launch(void* const* d_in, const int* in_sizes, int n_in,
                              void* d_out, int out_size, void* d_ws, size_t ws_size,
                              hipStream_t stream) {
  const float* lhs = (const float*)d_in[0];     // (16,512,768) f32
  const float* W = (const float*)d_in[1];       // (768,1024) f32
  const float* bias = (const float*)d_in[2];    // (1024,) f32
  const int* mask = (const int*)d_in[3];        // (16,512) i32
  const int* bbox = (const int*)d_in[4];        // (16,512,4) i32
  const int* labels = (const int*)d_in[5];      // (16,8,512,512) i32
  float* out = (float*)d_out;                   // [loss(1)] + logits (16,8,512,512) f32

  char* ws = (char*)d_ws;
  u16* lhsb = (u16*)(ws);                       // 12582912 B
  u16* wt = (u16*)(ws + 12582912);              // 1572864 B
  u16* qws = (u16*)(ws + 14155776);             // 8388608 B
  u16* kws = (u16*)(ws + 22544384);             // 8388608 B
  float2* tab = (float2*)(ws + 30932992);       // 131072 B
  float2* partials = (float2*)(ws + 31064064);  // 8192 B

  k_cvt_lhs<<<6144, 256, 0, stream>>>((const float4*)lhs, (ushort4*)lhsb);
  k_transpose_w<<<dim3(32, 24), dim3(32, 8), 0, stream>>>(W, wt);
  k_table<<<64, 256, 0, stream>>>(tab);
  k_gemm1<<<dim3(64, 8), 256, 0, stream>>>(lhsb, wt, bias, (const int2*)bbox, tab, qws, kws);
  k_logits_loss<<<dim3(8, 128), 256, 0, stream>>>(qws, kws, mask, labels, out, partials);
  k_final<<<1, 128, 0, stream>>>(partials, out);
}

// Round 4
// 106.590 us; speedup vs baseline: 2.0131x; 1.1005x over previous
//
#include <hip/hip_runtime.h>

typedef unsigned short u16;
typedef unsigned int u32;
typedef __attribute__((ext_vector_type(8))) short bf16x8;
typedef __attribute__((ext_vector_type(8))) unsigned short u16x8;
typedef __attribute__((ext_vector_type(4))) float f32x4;

#define GLOBAL_AS __attribute__((address_space(1)))
#define LDS_AS __attribute__((address_space(3)))

#define BIGV 1.0e12f
#define M0PIV 1.25e11f

__device__ __forceinline__ u16 f2bf(float f) {
  u32 u = __float_as_uint(f);
  u32 r = (u + 0x7fffu + ((u >> 16) & 1u)) >> 16;
  return (u16)r;
}
__device__ __forceinline__ float bf2f(u16 h) {
  return __uint_as_float(((u32)h) << 16);
}

// ---------------- prep kernels ----------------

__global__ __launch_bounds__(256) void k_cvt_lhs(const float4* __restrict__ in,
                                                 ushort4* __restrict__ out) {
  int t = blockIdx.x * 256 + threadIdx.x;  // 1572864 total
  float4 v = in[t];
  ushort4 o;
  o.x = f2bf(v.x); o.y = f2bf(v.y); o.z = f2bf(v.z); o.w = f2bf(v.w);
  out[t] = o;
}

__global__ __launch_bounds__(256) void k_transpose_w(const float* __restrict__ W,
                                                     u16* __restrict__ WT) {
  __shared__ float tile[32][33];
  int tx = threadIdx.x, ty = threadIdx.y;             // (32,8)
  int gx = blockIdx.x * 32, gy = blockIdx.y * 32;     // gx: cols of W(1024), gy: rows (768)
  #pragma unroll
  for (int i = 0; i < 4; ++i)
    tile[ty + 8 * i][tx] = W[(size_t)(gy + ty + 8 * i) * 1024 + gx + tx];
  __syncthreads();
  #pragma unroll
  for (int i = 0; i < 4; ++i)
    WT[(size_t)(gx + ty + 8 * i) * 768 + gy + tx] = f2bf(tile[tx][ty + 8 * i]);
}

__global__ __launch_bounds__(256) void k_table(float2* __restrict__ tab) {
  int t = blockIdx.x * 256 + threadIdx.x;  // 16384 = 1024 pos * 16 freq
  int p = t >> 4, i = t & 15;
  float freq = __expf(-0.57564627324851148f * (float)i);  // ln(10000)/16
  float ang = (float)p * freq;
  float s, c;
  sincosf(ang, &s, &c);
  tab[t] = make_float2(s, c);
}

// ------- stage 1: proj = lhs @ W + b, fused RoPE epilogue (bf16 MFMA, 128x128 tile, BK=64) -------

__global__ __launch_bounds__(256) void k_gemm1(const u16* __restrict__ A,   // [8192][768] bf16
                                               const u16* __restrict__ WT,  // [1024][768] bf16
                                               const float* __restrict__ bias,
                                               const int2* __restrict__ bbox2,  // (x,y) pairs stride 2
                                               const float2* __restrict__ tab,
                                               u16* __restrict__ qws,       // [128][512][64] bf16
                                               u16* __restrict__ kws) {
  __shared__ __align__(16) u16 As[128 * 64];
  __shared__ __align__(16) u16 Bs[128 * 64];
  const int tid = threadIdx.x;
  const int wave = tid >> 6, lane = tid & 63;
  const int lg = lane >> 4, lr = lane & 15;
  const int m0 = blockIdx.x * 128;
  const int e = blockIdx.y;
  const int n0 = e * 128;
  const int wr = wave >> 1, wc = wave & 1;

  f32x4 acc[4][4];
  #pragma unroll
  for (int i = 0; i < 4; ++i)
    #pragma unroll
    for (int j = 0; j < 4; ++j)
      acc[i][j] = (f32x4){0.f, 0.f, 0.f, 0.f};

  for (int k0 = 0; k0 < 768; k0 += 64) {
    #pragma unroll
    for (int i = 0; i < 4; ++i) {
      int u = (i * 4 + wave) * 64 + lane;
      int r = u >> 3, sl = u & 7;
      const u16* srcA = A + (size_t)(m0 + r) * 768 + k0 + ((sl ^ (r & 7)) * 8);
      __builtin_amdgcn_global_load_lds((const GLOBAL_AS void*)srcA,
                                       (LDS_AS void*)(As + (i * 4 + wave) * 512), 16, 0, 0);
      const u16* srcB = WT + (size_t)(n0 + r) * 768 + k0 + ((sl ^ (r & 7)) * 8);
      __builtin_amdgcn_global_load_lds((const GLOBAL_AS void*)srcB,
                                       (LDS_AS void*)(Bs + (i * 4 + wave) * 512), 16, 0, 0);
    }
    __syncthreads();
    #pragma unroll
    for (int ks = 0; ks < 2; ++ks) {
      bf16x8 af[4], bfr[4];
      #pragma unroll
      for (int mi = 0; mi < 4; ++mi) {
        int r = wr * 64 + mi * 16 + lr;
        int slot = (ks * 4 + lg) ^ (r & 7);
        af[mi] = *reinterpret_cast<const bf16x8*>(As + r * 64 + slot * 8);
      }
      #pragma unroll
      for (int ni = 0; ni < 4; ++ni) {
        int r = wc * 64 + ni * 16 + lr;
        int slot = (ks * 4 + lg) ^ (r & 7);
        bfr[ni] = *reinterpret_cast<const bf16x8*>(Bs + r * 64 + slot * 8);
      }
      #pragma unroll
      for (int mi = 0; mi < 4; ++mi)
        #pragma unroll
        for (int ni = 0; ni < 4; ++ni)
          acc[mi][ni] = __builtin_amdgcn_mfma_f32_16x16x32_bf16(af[mi], bfr[ni], acc[mi][ni], 0, 0, 0);
    }
    __syncthreads();
  }

  // epilogue: bias + RoPE (partner via shfl_xor(1)) + bf16 scatter
  float bv[4];
  #pragma unroll
  for (int ni = 0; ni < 4; ++ni) bv[ni] = bias[n0 + wc * 64 + ni * 16 + lr];

  #pragma unroll
  for (int mi = 0; mi < 4; ++mi) {
    #pragma unroll
    for (int q = 0; q < 4; ++q) {
      int m = m0 + wr * 64 + mi * 16 + lg * 4 + q;   // global row = b*512+s
      int bi = m >> 9, sdx = m & 511;
      int2 xy = bbox2[(bi << 9) + sdx];
      size_t rowbase = ((size_t)(bi * 8 + e) * 512 + sdx) << 6;
      #pragma unroll
      for (int ni = 0; ni < 4; ++ni) {
        int nloc = wc * 64 + ni * 16 + lr;   // 0..127 within entity
        int d = nloc & 63;
        float v = acc[mi][ni][q] + bv[ni];
        float p = __shfl_xor(v, 1);
        int pos = (d < 32) ? xy.x : xy.y;
        float2 sc = tab[pos * 16 + ((d & 31) >> 1)];  // (sin, cos)
        float res = (d & 1) ? (v * sc.y + p * sc.x) : (v * sc.y - p * sc.x);
        u16* dst = (nloc < 64) ? qws : kws;
        dst[rowbase + d] = f2bf(res);
      }
    }
  }
}

// ---------------- stage 2: pipelined logits + fixed-pivot LSE partial sums ----------------
// Single barrier per cc-iteration: barrier -> issue K-stage(cc+1) -> issue label/mask
// prefetch (VGPRs) -> MFMA(cc) -> epilogue consumes registers. Double-buffered Ks.
// neg side: pivot 0           -> sum_n += (1-y)*exp(L)        (masked underflow to 0)
// pos side: pivot M0PIV=BIG/8 -> sum_p += exp(min(apos,80))   (y=0 underflows to 0)

__global__ __launch_bounds__(256) void k_logits_loss(const u16* __restrict__ qws,
                                                     const u16* __restrict__ kws,
                                                     const int* __restrict__ mask,
                                                     const int* __restrict__ labels,
                                                     float* __restrict__ out,
                                                     float2* __restrict__ partials) {
  __shared__ __align__(16) u16 Qs[64 * 64];
  __shared__ __align__(16) u16 Ks[2][128 * 64];
  __shared__ float2 wred[4];
  const int tid = threadIdx.x;
  const int wave = tid >> 6, lane = tid & 63;
  const int lg = lane >> 4, lr = lane & 15;
  const int mb = blockIdx.x, be = blockIdx.y;   // mb fastest: blocks sharing K are adjacent
  const int b = be >> 3;
  const int m0 = mb * 64;

  const u16* qbase = qws + ((size_t)be * 512 + m0) * 64;
  const u16* kbase = kws + (size_t)be * 512 * 64;

  // stage Q block (64x64 bf16 = 512 x 16B units), XOR-swizzled source
  #pragma unroll
  for (int i = 0; i < 2; ++i) {
    int u = (i * 4 + wave) * 64 + lane;
    int r = u >> 3, sl = u & 7;
    const u16* src = qbase + r * 64 + ((sl ^ (r & 7)) * 8);
    __builtin_amdgcn_global_load_lds((const GLOBAL_AS void*)src,
                                     (LDS_AS void*)(Qs + (i * 4 + wave) * 512), 16, 0, 0);
  }
  // stage K tile 0 into Ks[0]
  #pragma unroll
  for (int i = 0; i < 4; ++i) {
    int u = (i * 4 + wave) * 64 + lane;
    int r = u >> 3, sl = u & 7;
    const u16* src = kbase + (size_t)r * 64 + ((sl ^ (r & 7)) * 8);
    __builtin_amdgcn_global_load_lds((const GLOBAL_AS void*)src,
                                     (LDS_AS void*)(Ks[0] + (i * 4 + wave) * 512), 16, 0, 0);
  }

  // per-thread row block: m = m0 + wave*16 + lg*4 + q  (q=0..3)
  const int mrow = m0 + wave * 16 + lg * 4;
  const size_t lrowbase = (((size_t)be * 512) + mrow) * 512;  // + q*512 + n

  float sum_n = 0.f, sum_p = 0.f;

  for (int cc = 0; cc < 4; ++cc) {
    __syncthreads();   // staging(cc) complete; Ks[(cc+1)&1] free (MFMA(cc-1) done)

    // issue K-stage for cc+1 (flies under MFMA + epilogue)
    if (cc < 3) {
      #pragma unroll
      for (int i = 0; i < 4; ++i) {
        int u = (i * 4 + wave) * 64 + lane;
        int r = u >> 3, sl = u & 7;
        const u16* src = kbase + (size_t)((cc + 1) * 128 + r) * 64 + ((sl ^ (r & 7)) * 8);
        __builtin_amdgcn_global_load_lds((const GLOBAL_AS void*)src,
                                         (LDS_AS void*)(Ks[(cc + 1) & 1] + (i * 4 + wave) * 512), 16, 0, 0);
      }
    }

    // prefetch labels (32 dwords) + mask (8 dwords) into registers
    int lab[8][4];
    float padv[8];
    #pragma unroll
    for (int ni = 0; ni < 8; ++ni) {
      int n = cc * 128 + ni * 16 + lr;
      padv[ni] = (float)mask[(b << 9) + n];
      #pragma unroll
      for (int q = 0; q < 4; ++q)
        lab[ni][q] = labels[lrowbase + (size_t)q * 512 + n];
    }

    // MFMA on Ks[cc&1]
    const u16* KsBuf = Ks[cc & 1];
    f32x4 acc[8];
    #pragma unroll
    for (int ni = 0; ni < 8; ++ni) acc[ni] = (f32x4){0.f, 0.f, 0.f, 0.f};

    #pragma unroll
    for (int ks = 0; ks < 2; ++ks) {
      bf16x8 a0;
      {
        int r = wave * 16 + lr;
        int slot = (ks * 4 + lg) ^ (r & 7);
        a0 = *reinterpret_cast<const bf16x8*>(Qs + r * 64 + slot * 8);
      }
      #pragma unroll
      for (int ni = 0; ni < 8; ++ni) {
        int r = ni * 16 + lr;
        int slot = (ks * 4 + lg) ^ (r & 7);
        bf16x8 bv = *reinterpret_cast<const bf16x8*>(KsBuf + r * 64 + slot * 8);
        acc[ni] = __builtin_amdgcn_mfma_f32_16x16x32_bf16(a0, bv, acc[ni], 0, 0, 0);
      }
    }

    // epilogue: all operands in registers
    #pragma unroll
    for (int ni = 0; ni < 8; ++ni) {
      int n = cc * 128 + ni * 16 + lr;
      float s = padv[ni] * 0.125f;
      float off = (padv[ni] - 1.f) * 1.25e11f;   // = -(1-pad)*BIG/8
      #pragma unroll
      for (int q = 0; q < 4; ++q) {
        float L = acc[ni][q] * s + off;
        if (mrow + q > n) L -= 1.25e11f;
        out[1 + lrowbase + (size_t)q * 512 + n] = L;
        float fy = (float)lab[ni][q];
        float e1 = __expf(L);                        // masked rows underflow to exactly 0
        sum_n += (1.f - fy) * e1;
        float ap = fy * (-L - M0PIV) + (fy - 1.f) * 1.0e13f;  // y=0 -> -1e13 -> exp 0
        sum_p += __expf(fminf(ap, 80.f));
      }
    }
  }

  // reduce plain sums across the wave, then block
  #pragma unroll
  for (int off = 32; off > 0; off >>= 1) {
    sum_n += __shfl_xor(sum_n, off);
    sum_p += __shfl_xor(sum_p, off);
  }
  if (lane == 0) wred[wave] = make_float2(sum_n, sum_p);
  __syncthreads();
  if (tid == 0) {
    float2 r0 = wred[0];
    for (int w = 1; w < 4; ++w) {
      float2 rw = wred[w];
      r0.x += rw.x;
      r0.y += rw.y;
    }
    partials[be * 8 + mb] = r0;
  }
}

// ---------------- final: combine partials, mean, write loss ----------------

__global__ __launch_bounds__(128) void k_final(const float2* __restrict__ partials,
                                               float* __restrict__ out) {
  __shared__ float red[128];
  int t = threadIdx.x;  // = be
  float Sn = 0.f, Sp = 0.f;
  for (int mb = 0; mb < 8; ++mb) {
    float2 p = partials[t * 8 + mb];
    Sn += p.x;
    Sp += p.y;
  }
  float neg = logf(1.f + Sn);                        // appended-zero entry = +1 at pivot 0
  float pos = (Sp > 0.f) ? (M0PIV + logf(Sp)) : 0.f; // zero entry underflows at pivot M0
  red[t] = neg + pos;
  __syncthreads();
  if (t == 0) {
    float s = 0.f;
    for (int i = 0; i < 128; ++i) s += red[i];
    out[0] = s * (1.f / 128.f);
  }
}

// ---------------- launch ----------------

extern "C" void kernel_launch(void* const* d_in, const int* in_sizes, int n_in,
                              void* d_out, int out_size, void* d_ws, size_t ws_size,
                              hipStream_t stream) {
  const float* lhs = (const float*)d_in[0];     // (16,512,768) f32
  const float* W = (const float*)d_in[1];       // (768,1024) f32
  const float* bias = (const float*)d_in[2];    // (1024,) f32
  const int* mask = (const int*)d_in[3];        // (16,512) i32
  const int* bbox = (const int*)d_in[4];        // (16,512,4) i32
  const int* labels = (const int*)d_in[5];      // (16,8,512,512) i32
  float* out = (float*)d_out;                   // [loss(1)] + logits (16,8,512,512) f32

  char* ws = (char*)d_ws;
  u16* lhsb = (u16*)(ws);                       // 12582912 B
  u16* wt = (u16*)(ws + 12582912);              // 1572864 B
  u16* qws = (u16*)(ws + 14155776);             // 8388608 B
  u16* kws = (u16*)(ws + 22544384);             // 8388608 B
  float2* tab = (float2*)(ws + 30932992);       // 131072 B
  float2* partials = (float2*)(ws + 31064064);  // 8192 B

  k_cvt_lhs<<<6144, 256, 0, stream>>>((const float4*)lhs, (ushort4*)lhsb);
  k_transpose_w<<<dim3(32, 24), dim3(32, 8), 0, stream>>>(W, wt);
  k_table<<<64, 256, 0, stream>>>(tab);
  k_gemm1<<<dim3(64, 8), 256, 0, stream>>>(lhsb, wt, bias, (const int2*)bbox, tab, qws, kws);
  k_logits_loss<<<dim3(8, 128), 256, 0, stream>>>(qws, kws, mask, labels, out, partials);
  k_final<<<1, 128, 0, stream>>>(partials, out);
}